// Round 3
// baseline (1812.529 us; speedup 1.0000x reference)
//
#include <hip/hip_runtime.h>
#include <stdint.h>

typedef unsigned short u16;
typedef __bf16 bf16x8 __attribute__((ext_vector_type(8)));
typedef float f32x4 __attribute__((ext_vector_type(4)));

#define AS1 __attribute__((address_space(1)))
#define AS3 __attribute__((address_space(3)))

// async global->LDS, 16B per lane. HW writes wave-uniform base + lane*16.
static __device__ __forceinline__ void gload16(const void* g, void* l) {
  __builtin_amdgcn_global_load_lds((const AS1 unsigned int*)g,
                                   (AS3 unsigned int*)l, 16, 0, 0);
}

static __device__ __forceinline__ u16 f2bf(float f) {
  unsigned u = __float_as_uint(f);
  u += 0x7fffu + ((u >> 16) & 1u);   // RNE; inputs are finite/tame
  return (u16)(u >> 16);
}

union BF8 { uint4 u; bf16x8 b; };
static __device__ __forceinline__ bf16x8 ldg_bf8(const u16* p) {
  BF8 t; t.u = *(const uint4*)p; return t.b;
}

// ---------------------------------------------------------------------------
// Transpose + fp32->bf16 convert: in (L,R,C) f32 -> out (L,C,R) bf16.
// grid = (C/32, R/32, L), block = 256
// ---------------------------------------------------------------------------
__global__ __launch_bounds__(256) void transpose_bf16(
    const float* __restrict__ in, u16* __restrict__ out, int R, int C)
{
  __shared__ float t[32][33];
  const size_t base = (size_t)blockIdx.z * R * C;
  const float* ip = in + base;
  u16* op = out + base;
  const int c0 = blockIdx.x * 32, r0 = blockIdx.y * 32;
  const int tx = threadIdx.x & 31, ty = threadIdx.x >> 5;  // 32 x 8
#pragma unroll
  for (int i = 0; i < 4; i++)
    t[ty + i * 8][tx] = ip[(size_t)(r0 + ty + i * 8) * C + (c0 + tx)];
  __syncthreads();
#pragma unroll
  for (int i = 0; i < 4; i++)
    op[(size_t)(c0 + ty + i * 8) * R + (r0 + tx)] = f2bf(t[tx][ty + i * 8]);
}

// ---------------------------------------------------------------------------
// Embedding gather: h[s][:] = tok_emb[tok[s]][:]. grid=2048, block=256
// ---------------------------------------------------------------------------
__global__ __launch_bounds__(256) void embed_k(
    const int* __restrict__ tok, const float* __restrict__ emb, float* __restrict__ h)
{
  const int s = blockIdx.x;
  const int t = tok[s];
  ((float4*)(h + (size_t)s * 1024))[threadIdx.x] =
      ((const float4*)(emb + (size_t)t * 1024))[threadIdx.x];
}

// ---------------------------------------------------------------------------
// RMSNorm row -> bf16. grid=2048 (one block/row), block=256 (4 elems/thread)
// ---------------------------------------------------------------------------
__global__ __launch_bounds__(256) void rmsnorm_bf16(
    const float* __restrict__ x, const float* __restrict__ w, u16* __restrict__ y)
{
  const int s = blockIdx.x, tid = threadIdx.x;
  const float4 v = ((const float4*)(x + (size_t)s * 1024))[tid];
  float ss = v.x * v.x + v.y * v.y + v.z * v.z + v.w * v.w;
#pragma unroll
  for (int off = 32; off; off >>= 1) ss += __shfl_xor(ss, off);
  __shared__ float red[4];
  if ((tid & 63) == 0) red[tid >> 6] = ss;
  __syncthreads();
  const float tot = red[0] + red[1] + red[2] + red[3];
  const float sc = rsqrtf(tot * (1.0f / 1024.0f) + 1e-6f);
  const float4 wv = ((const float4*)w)[tid];
  ushort4 o;
  o.x = f2bf(v.x * sc * wv.x);
  o.y = f2bf(v.y * sc * wv.y);
  o.z = f2bf(v.z * sc * wv.z);
  o.w = f2bf(v.w * sc * wv.w);
  ((ushort4*)(y + (size_t)s * 1024))[tid] = o;
}

// ---------------------------------------------------------------------------
// GEMM: C(MxN) [f32] = A(MxK)[bf16, lda=K] @ Bt(NxK)[bf16, ldb=K]^T  (+C if doAdd)
// m97 structure: 128x128 tile, BK=32, 4 waves (2x2), 4x4 16x16x32 frags/wave,
// global_load_lds width=16 staging. grid=(N/128, M/128, z); z picks B/C set.
// ---------------------------------------------------------------------------
__global__ __launch_bounds__(256) void gemm_bt(
    int M, int N, int K,
    const u16* __restrict__ A,
    const u16* __restrict__ Bz0, const u16* __restrict__ Bz1, const u16* __restrict__ Bz2,
    float* __restrict__ Cz0, float* __restrict__ Cz1, float* __restrict__ Cz2,
    int doAdd)
{
  const u16* B = (blockIdx.z == 0) ? Bz0 : (blockIdx.z == 1) ? Bz1 : Bz2;
  float*    C = (blockIdx.z == 0) ? Cz0 : (blockIdx.z == 1) ? Cz1 : Cz2;
  __shared__ u16 As[128 * 32];
  __shared__ u16 Bs[128 * 32];
  const int tid = threadIdx.x;
  const int wave = tid >> 6, lane = tid & 63;
  const int lm = lane & 15, quad = lane >> 4;
  const int wm = wave >> 1, wn = wave & 1;
  const int m0 = blockIdx.y * 128, n0 = blockIdx.x * 128;

  const int c0 = tid, c1 = tid + 256;
  const u16* ga0 = A + (size_t)(m0 + (c0 >> 2)) * K + (c0 & 3) * 8;
  const u16* ga1 = A + (size_t)(m0 + (c1 >> 2)) * K + (c1 & 3) * 8;
  const u16* gb0 = B + (size_t)(n0 + (c0 >> 2)) * K + (c0 & 3) * 8;
  const u16* gb1 = B + (size_t)(n0 + (c1 >> 2)) * K + (c1 & 3) * 8;
  u16* la0 = &As[c0 * 8];
  u16* la1 = &As[c1 * 8];
  u16* lb0 = &Bs[c0 * 8];
  u16* lb1 = &Bs[c1 * 8];

  f32x4 acc[4][4];
#pragma unroll
  for (int i = 0; i < 4; i++)
#pragma unroll
    for (int j = 0; j < 4; j++) acc[i][j] = (f32x4){0.f, 0.f, 0.f, 0.f};

  const u16* arp = &As[(wm * 64 + lm) * 32 + quad * 8];
  const u16* brp = &Bs[(wn * 64 + lm) * 32 + quad * 8];

  for (int k0 = 0; k0 < K; k0 += 32) {
    __syncthreads();
    gload16(ga0 + k0, la0);
    gload16(ga1 + k0, la1);
    gload16(gb0 + k0, lb0);
    gload16(gb1 + k0, lb1);
    __syncthreads();
    bf16x8 af[4], bfv[4];
#pragma unroll
    for (int mi = 0; mi < 4; mi++) af[mi] = *(const bf16x8*)(arp + mi * 16 * 32);
#pragma unroll
    for (int ni = 0; ni < 4; ni++) bfv[ni] = *(const bf16x8*)(brp + ni * 16 * 32);
#pragma unroll
    for (int mi = 0; mi < 4; mi++)
#pragma unroll
      for (int ni = 0; ni < 4; ni++)
        acc[mi][ni] = __builtin_amdgcn_mfma_f32_16x16x32_bf16(af[mi], bfv[ni], acc[mi][ni], 0, 0, 0);
  }

#pragma unroll
  for (int mi = 0; mi < 4; mi++) {
    const int row = m0 + wm * 64 + mi * 16 + quad * 4;
#pragma unroll
    for (int ni = 0; ni < 4; ni++) {
      const int col = n0 + wn * 64 + ni * 16 + lm;
      float* cp = C + (size_t)row * N + col;
      if (doAdd) {
#pragma unroll
        for (int r = 0; r < 4; r++) cp[(size_t)r * N] += acc[mi][ni][r];
      } else {
#pragma unroll
        for (int r = 0; r < 4; r++) cp[(size_t)r * N] = acc[mi][ni][r];
      }
    }
  }
}

// ---------------------------------------------------------------------------
// GEMM 128x64 tile variant, always C += A@B^T. grid=(N/64, M/128), block=256.
// ---------------------------------------------------------------------------
__global__ __launch_bounds__(256) void gemm_bt64(
    int M, int N, int K, const u16* __restrict__ A, const u16* __restrict__ B,
    float* __restrict__ C)
{
  __shared__ u16 As[128 * 32];
  __shared__ u16 Bs[64 * 32];
  const int tid = threadIdx.x;
  const int wave = tid >> 6, lane = tid & 63;
  const int lm = lane & 15, quad = lane >> 4;
  const int m0 = blockIdx.y * 128, n0 = blockIdx.x * 64;

  const int c0 = tid, c1 = tid + 256;
  const u16* ga0 = A + (size_t)(m0 + (c0 >> 2)) * K + (c0 & 3) * 8;
  const u16* ga1 = A + (size_t)(m0 + (c1 >> 2)) * K + (c1 & 3) * 8;
  const u16* gb0 = B + (size_t)(n0 + (c0 >> 2)) * K + (c0 & 3) * 8;
  u16* la0 = &As[c0 * 8];
  u16* la1 = &As[c1 * 8];
  u16* lb0 = &Bs[c0 * 8];

  f32x4 acc[2][4];
#pragma unroll
  for (int i = 0; i < 2; i++)
#pragma unroll
    for (int j = 0; j < 4; j++) acc[i][j] = (f32x4){0.f, 0.f, 0.f, 0.f};

  const u16* arp = &As[(wave * 32 + lm) * 32 + quad * 8];
  const u16* brp = &Bs[lm * 32 + quad * 8];

  for (int k0 = 0; k0 < K; k0 += 32) {
    __syncthreads();
    gload16(ga0 + k0, la0);
    gload16(ga1 + k0, la1);
    gload16(gb0 + k0, lb0);
    __syncthreads();
    bf16x8 af[2], bfv[4];
#pragma unroll
    for (int mi = 0; mi < 2; mi++) af[mi] = *(const bf16x8*)(arp + mi * 16 * 32);
#pragma unroll
    for (int ni = 0; ni < 4; ni++) bfv[ni] = *(const bf16x8*)(brp + ni * 16 * 32);
#pragma unroll
    for (int mi = 0; mi < 2; mi++)
#pragma unroll
      for (int ni = 0; ni < 4; ni++)
        acc[mi][ni] = __builtin_amdgcn_mfma_f32_16x16x32_bf16(af[mi], bfv[ni], acc[mi][ni], 0, 0, 0);
  }

#pragma unroll
  for (int mi = 0; mi < 2; mi++) {
    const int row = m0 + wave * 32 + mi * 16 + quad * 4;
#pragma unroll
    for (int ni = 0; ni < 4; ni++) {
      const int col = n0 + ni * 16 + lm;
      float* cp = C + (size_t)row * N + col;
#pragma unroll
      for (int r = 0; r < 4; r++) cp[(size_t)r * N] += acc[mi][ni][r];
    }
  }
}

// ---------------------------------------------------------------------------
// RoPE on q,k (fp32 in) -> bf16 out. grid = 4096, block = 256
// ---------------------------------------------------------------------------
__global__ __launch_bounds__(256) void rope_qk(
    const float* __restrict__ qf, const float* __restrict__ kf,
    u16* __restrict__ qb, u16* __restrict__ kb)
{
  const int idx = blockIdx.x * 256 + threadIdx.x;
  const int s = idx >> 9;          // 512 pairs per position
  const int p = idx & 511;
  const int h = p >> 5, i = p & 31;
  const size_t o = (size_t)s * 1024 + h * 64 + 2 * i;
  const float freq = __expf((float)i * (-9.210340371976184f / 32.0f)); // theta^{-2i/64}
  const float ang = (float)s * freq;
  float sn, cs;
  sincosf(ang, &sn, &cs);
  const float2 q = *(const float2*)(qf + o);
  const float2 k = *(const float2*)(kf + o);
  ushort2 qo, ko;
  qo.x = f2bf(q.x * cs - q.y * sn); qo.y = f2bf(q.x * sn + q.y * cs);
  ko.x = f2bf(k.x * cs - k.y * sn); ko.y = f2bf(k.x * sn + k.y * cs);
  *(ushort2*)(qb + o) = qo;
  *(ushort2*)(kb + o) = ko;
}

// ---------------------------------------------------------------------------
// Flash attention v2, causal, bf16 MFMA — SWAPPED-QK^T (no LDS, no P round
// trip). grid=(32, 16 heads), block=256, 4 independent waves (16 queries ea).
//
// QK: S_tile = mfma(A=K, B=Q) (operand swap is free: A/B frag layouts are
// symmetric, same register loads — same pattern gemm_bt uses for its B^T
// operand). D layout: col=lm=query, row=4*quad+r=key => each lane holds 16
// scores for ONE query (keys 16j+4q+r, j=0..3) => softmax is in-lane: 15
// fmax + 2 shfl_xor, exp2 in-lane, 15 adds + 2 shfl_xor. No LDS round trip
// for P: PV uses the contraction mapping (quad,jj)->key =
// 32h+16*(jj>=4)+4*quad+(jj&3) on BOTH A (P, packed in-lane) and B (V,
// loaded 2x8B in that pattern). Any bijection is legal if both operands
// agree. o/lrun epilogue layout unchanged (D of PV: row=4q+r=query,
// col=lm=d). alpha/lrun cross from query=lm to query=4q+r via 4 shfls.
// NOTE: no s_setprio here (removed round 3 — only behavioral unknown in the
// round-2 post-timing divergence; data-flow audit of everything else clean).
// ---------------------------------------------------------------------------
struct KFr { bf16x8 b[8]; };

__global__ __launch_bounds__(256) void attn_fa(
    const u16* __restrict__ Q, const u16* __restrict__ Kb,
    const u16* __restrict__ Vt, u16* __restrict__ O)
{
  const int head = blockIdx.y;
  const int wave = threadIdx.x >> 6, lane = threadIdx.x & 63;
  const int lm = lane & 15, quad = lane >> 4;
  const int qblk = 31 - blockIdx.x;          // longest first
  const int q0 = qblk * 64 + wave * 16;
  const int nc = qblk + 1;                   // 64-key chunks (uniform per block)
  const float sc_l2 = 0.125f * 1.4426950408889634f;  // 1/sqrt(64) * log2(e)
  const int qrow = q0 + lm;                  // this lane's query (softmax layout)

  const u16* qp = Q + (size_t)(q0 + lm) * 1024 + head * 64 + quad * 8;
  const bf16x8 aq0 = ldg_bf8(qp);        // Q[q=lm][d=quad*8+j], d 0..31 (B-frag)
  const bf16x8 aq1 = ldg_bf8(qp + 32);   // d 32..63
  const u16* vbase = Vt + (size_t)(head * 64 + lm) * 2048;

  f32x4 o[4];
#pragma unroll
  for (int i = 0; i < 4; i++) o[i] = (f32x4){0.f, 0.f, 0.f, 0.f};
  float mrun = -1e30f;   // per-lane running max (log2 domain), query qrow
  float lrun = 0.f;      // per-lane running denom, query qrow

  auto loadK = [&](KFr& kr, int kc) {
    const u16* kp = Kb + (size_t)(kc + lm) * 1024 + head * 64 + quad * 8;
#pragma unroll
    for (int j = 0; j < 4; j++) {
      kr.b[j * 2 + 0] = ldg_bf8(kp + (size_t)j * 16 * 1024);        // keys kc+16j+lm, d lo
      kr.b[j * 2 + 1] = ldg_bf8(kp + (size_t)j * 16 * 1024 + 32);   //                 d hi
    }
  };

  auto compute = [&](const KFr& kr, int kc) {
    // V loads issued first; consumed only after softmax. B-frag pattern:
    // (quad,jj) -> key = kc + 32h + 16*(jj>=4) + 4*quad + (jj&3), d=nd*16+lm.
    BF8 vv[2][4];
#pragma unroll
    for (int h = 0; h < 2; h++)
#pragma unroll
      for (int nd = 0; nd < 4; nd++) {
        const u16* vp = vbase + (size_t)nd * 16 * 2048 + kc + h * 32 + quad * 4;
        const uint2 lo = *(const uint2*)vp;          // keys +0..3
        const uint2 hi = *(const uint2*)(vp + 16);   // keys +16..19
        vv[h][nd].u = (uint4){lo.x, lo.y, hi.x, hi.y};
      }
    const f32x4 z = (f32x4){0.f, 0.f, 0.f, 0.f};
    f32x4 S[4];
#pragma unroll
    for (int j = 0; j < 4; j++) {
      S[j] = __builtin_amdgcn_mfma_f32_16x16x32_bf16(kr.b[j * 2 + 0], aq0, z, 0, 0, 0);
      S[j] = __builtin_amdgcn_mfma_f32_16x16x32_bf16(kr.b[j * 2 + 1], aq1, S[j], 0, 0, 0);
    }
    // per-lane: 16 scores for query qrow, key(j,r) = kc + 16j + 4*quad + r
    float p[4][4];
#pragma unroll
    for (int j = 0; j < 4; j++)
#pragma unroll
      for (int r = 0; r < 4; r++) p[j][r] = S[j][r] * sc_l2;
    if (kc + 63 > q0) {                       // wave-uniform: chunk hits diagonal
#pragma unroll
      for (int j = 0; j < 4; j++)
#pragma unroll
        for (int r = 0; r < 4; r++)
          if (kc + 16 * j + 4 * quad + r > qrow) p[j][r] = -1e30f;
    }
    float mx = -1e30f;
#pragma unroll
    for (int j = 0; j < 4; j++)
#pragma unroll
      for (int r = 0; r < 4; r++) mx = fmaxf(mx, p[j][r]);
    mx = fmaxf(mx, __shfl_xor(mx, 16));
    mx = fmaxf(mx, __shfl_xor(mx, 32));       // now quad-uniform per query lm
    const float mnew = fmaxf(mrun, mx);
    const float alpha = exp2f(mrun - mnew);
    mrun = mnew;
    float rs = 0.f;
#pragma unroll
    for (int j = 0; j < 4; j++)
#pragma unroll
      for (int r = 0; r < 4; r++) {
        p[j][r] = exp2f(p[j][r] - mnew);
        rs += p[j][r];
      }
    rs += __shfl_xor(rs, 16);
    rs += __shfl_xor(rs, 32);
    lrun = lrun * alpha + rs;
    // alpha lives at query=lm; o rows are query=4*quad+r -> broadcast
    float alr[4];
#pragma unroll
    for (int r = 0; r < 4; r++) alr[r] = __shfl(alpha, quad * 4 + r);
#pragma unroll
    for (int nd = 0; nd < 4; nd++)
#pragma unroll
      for (int r = 0; r < 4; r++) o[nd][r] *= alr[r];
    // pack P A-frags fully in-lane: fa[h] jj<4 = p[2h][jj], jj>=4 = p[2h+1][jj-4]
    BF8 fa[2];
#pragma unroll
    for (int h = 0; h < 2; h++) {
      u16* s = (u16*)&fa[h];
#pragma unroll
      for (int r = 0; r < 4; r++) {
        s[r]     = f2bf(p[2 * h][r]);
        s[4 + r] = f2bf(p[2 * h + 1][r]);
      }
    }
#pragma unroll
    for (int h = 0; h < 2; h++)
#pragma unroll
      for (int nd = 0; nd < 4; nd++)
        o[nd] = __builtin_amdgcn_mfma_f32_16x16x32_bf16(fa[h].b, vv[h][nd].b, o[nd], 0, 0, 0);
  };

  KFr kA, kB;
  loadK(kA, 0);
  int c = 0;
  while (true) {
    if (c + 1 < nc) loadK(kB, (c + 1) * 64);
    compute(kA, c * 64);
    if (++c == nc) break;
    if (c + 1 < nc) loadK(kA, (c + 1) * 64);
    compute(kB, c * 64);
    if (++c == nc) break;
  }

  // lrun lives at query=lm; o rows are query=4*quad+r -> broadcast
#pragma unroll
  for (int r = 0; r < 4; r++) {
    const float linv = 1.0f / __shfl(lrun, quad * 4 + r);
    const int row = q0 + quad * 4 + r;
    u16* op = O + (size_t)row * 1024 + head * 64 + lm;
#pragma unroll
    for (int nd = 0; nd < 4; nd++) op[nd * 16] = f2bf(o[nd][r] * linv);
  }
}

// ---------------------------------------------------------------------------
// u = bf16( silu(g1) * g3 ). grid=5632, block=256, float4 per thread.
// ---------------------------------------------------------------------------
__global__ __launch_bounds__(256) void silu_mul(
    const float* __restrict__ g1, const float* __restrict__ g3, u16* __restrict__ u)
{
  const int idx = blockIdx.x * 256 + threadIdx.x;
  const float4 a = ((const float4*)g1)[idx];
  const float4 b = ((const float4*)g3)[idx];
  ushort4 o;
  o.x = f2bf(a.x / (1.f + __expf(-a.x)) * b.x);
  o.y = f2bf(a.y / (1.f + __expf(-a.y)) * b.y);
  o.z = f2bf(a.z / (1.f + __expf(-a.z)) * b.z);
  o.w = f2bf(a.w / (1.f + __expf(-a.w)) * b.w);
  ((ushort4*)u)[idx] = o;
}

// ---------------------------------------------------------------------------
// Final RMSNorm of last row (fp32 out). 1 block, 256 threads.
// ---------------------------------------------------------------------------
__global__ __launch_bounds__(256) void final_norm(
    const float* __restrict__ h, const float* __restrict__ w, float* __restrict__ xn)
{
  const int tid = threadIdx.x;
  const float4 v = ((const float4*)(h + (size_t)2047 * 1024))[tid];
  float ss = v.x * v.x + v.y * v.y + v.z * v.z + v.w * v.w;
#pragma unroll
  for (int off = 32; off; off >>= 1) ss += __shfl_xor(ss, off);
  __shared__ float red[4];
  if ((tid & 63) == 0) red[tid >> 6] = ss;
  __syncthreads();
  const float tot = red[0] + red[1] + red[2] + red[3];
  const float sc = rsqrtf(tot * (1.0f / 1024.0f) + 1e-6f);
  const float4 wv = ((const float4*)w)[tid];
  float4 o;
  o.x = v.x * sc * wv.x; o.y = v.y * sc * wv.y;
  o.z = v.z * sc * wv.z; o.w = v.w * sc * wv.w;
  ((float4*)xn)[tid] = o;
}

// ---------------------------------------------------------------------------
// logits[v] += sum over 256-d slice of xn[d]*Wout[d][v]. grid=(125,4), fp32.
// ---------------------------------------------------------------------------
__global__ __launch_bounds__(256) void logits_k(
    const float* __restrict__ xn, const float* __restrict__ Wout, float* __restrict__ out)
{
  const int v = blockIdx.x * 256 + threadIdx.x;
  const int dp = blockIdx.y;
  const float* xp = xn + dp * 256;
  const float* wp = Wout + (size_t)dp * 256 * 32000 + v;
  float acc = 0.f;
#pragma unroll 8
  for (int d = 0; d < 256; d++) acc = fmaf(xp[d], wp[(size_t)d * 32000], acc);
  atomicAdd(out + v, acc);
}

// ---------------------------------------------------------------------------
extern "C" void kernel_launch(void* const* d_in, const int* in_sizes, int n_in,
                              void* d_out, int out_size, void* d_ws, size_t ws_size,
                              hipStream_t stream) {
  const int S = 2048, D = 1024, HFF = 2816, L = 4;
  const int* tokens = (const int*)d_in[0];
  const float* tok_emb = (const float*)d_in[2];
  const float* Wq = (const float*)d_in[3];
  const float* Wk = (const float*)d_in[4];
  const float* Wv = (const float*)d_in[5];
  const float* Wo = (const float*)d_in[6];
  const float* W1 = (const float*)d_in[7];
  const float* W2 = (const float*)d_in[8];   // dict order: W2 before W3
  const float* W3 = (const float*)d_in[9];
  const float* anw  = (const float*)d_in[10];
  const float* fnw  = (const float*)d_in[11];
  const float* finw = (const float*)d_in[12];
  const float* Wout = (const float*)d_in[13];

  char* w = (char*)d_ws;
  size_t off = 0;
  auto take = [&](size_t b) { size_t o = off; off += (b + 255) & ~(size_t)255; return o; };
  const size_t szDD = (size_t)L * D * D * 2;       // 8 MB bf16
  const size_t szDH = (size_t)L * D * HFF * 2;     // 23 MB bf16
  u16* WqT = (u16*)(w + take(szDD));
  u16* WkT = (u16*)(w + take(szDD));
  u16* WvT = (u16*)(w + take(szDD));
  u16* WoT = (u16*)(w + take(szDD));
  u16* W1T = (u16*)(w + take(szDH));
  u16* W3T = (u16*)(w + take(szDH));
  u16* W2T = (u16*)(w + take(szDH));
  float* h  = (float*)(w + take((size_t)S * D * 4));
  u16*   xb = (u16*)(w + take((size_t)S * D * 2));
  const size_t region = take((size_t)2 * S * HFF * 4 + (size_t)S * HFF * 2);
  float* qf = (float*)(w + region);
  float* kf = qf + (size_t)S * D;
  float* vf = kf + (size_t)S * D;
  u16* qbb = (u16*)(vf + (size_t)S * D);
  u16* kbb = qbb + (size_t)S * D;
  u16* vTb = kbb + (size_t)S * D;
  u16* ob  = vTb + (size_t)S * D;
  float* g1 = (float*)(w + region);
  float* g3 = g1 + (size_t)S * HFF;
  u16*  ub  = (u16*)(g3 + (size_t)S * HFF);
  float* xn = (float*)(w + take(4096));
  (void)ws_size; (void)in_sizes; (void)n_in; (void)out_size;

  const dim3 blk(256);
  transpose_bf16<<<dim3(32, 32, 4), blk, 0, stream>>>(Wq, WqT, D, D);
  transpose_bf16<<<dim3(32, 32, 4), blk, 0, stream>>>(Wk, WkT, D, D);
  transpose_bf16<<<dim3(32, 32, 4), blk, 0, stream>>>(Wv, WvT, D, D);
  transpose_bf16<<<dim3(32, 32, 4), blk, 0, stream>>>(Wo, WoT, D, D);
  transpose_bf16<<<dim3(88, 32, 4), blk, 0, stream>>>(W1, W1T, D, HFF);
  transpose_bf16<<<dim3(88, 32, 4), blk, 0, stream>>>(W3, W3T, D, HFF);
  transpose_bf16<<<dim3(32, 88, 4), blk, 0, stream>>>(W2, W2T, HFF, D);
  embed_k<<<2048, blk, 0, stream>>>(tokens, tok_emb, h);

  for (int l = 0; l < L; l++) {
    const size_t oDD = (size_t)l * D * D;
    const size_t oDH = (size_t)l * D * HFF;
    rmsnorm_bf16<<<2048, blk, 0, stream>>>(h, anw + l * D, xb);
    gemm_bt<<<dim3(8, 16, 3), blk, 0, stream>>>(S, D, D, xb,
        WqT + oDD, WkT + oDD, WvT + oDD, qf, kf, vf, 0);
    rope_qk<<<4096, blk, 0, stream>>>(qf, kf, qbb, kbb);
    transpose_bf16<<<dim3(32, 64, 1), blk, 0, stream>>>(vf, vTb, S, D);
    attn_fa<<<dim3(32, 16), blk, 0, stream>>>(qbb, kbb, vTb, ob);
    gemm_bt64<<<dim3(16, 16), blk, 0, stream>>>(S, D, D, ob, WoT + oDD, h);
    rmsnorm_bf16<<<2048, blk, 0, stream>>>(h, fnw + l * D, xb);
    gemm_bt<<<dim3(22, 16, 2), blk, 0, stream>>>(S, HFF, D, xb,
        W1T + oDH, W3T + oDH, W3T + oDH, g1, g3, g3, 0);
    silu_mul<<<5632, blk, 0, stream>>>(g1, g3, ub);
    gemm_bt64<<<dim3(16, 16), blk, 0, stream>>>(S, D, HFF, ub, W2T + oDH, h);
  }
  final_norm<<<1, blk, 0, stream>>>(h, finw, xn);
  hipMemsetAsync(d_out, 0, 32000 * sizeof(float), stream);
  logits_k<<<dim3(125, 4), blk, 0, stream>>>(xn, Wout, (float*)d_out);
}

// Round 4
// 1375.362 us; speedup vs baseline: 1.3179x; 1.3179x over previous
//
#include <hip/hip_runtime.h>
#include <stdint.h>

typedef unsigned short u16;
typedef __bf16 bf16x8 __attribute__((ext_vector_type(8)));
typedef float f32x4 __attribute__((ext_vector_type(4)));

#define AS1 __attribute__((address_space(1)))
#define AS3 __attribute__((address_space(3)))

// async global->LDS, 16B per lane. HW writes wave-uniform base + lane*16.
static __device__ __forceinline__ void gload16(const void* g, void* l) {
  __builtin_amdgcn_global_load_lds((const AS1 unsigned int*)g,
                                   (AS3 unsigned int*)l, 16, 0, 0);
}

static __device__ __forceinline__ u16 f2bf(float f) {
  unsigned u = __float_as_uint(f);
  u += 0x7fffu + ((u >> 16) & 1u);   // RNE; inputs are finite/tame
  return (u16)(u >> 16);
}

union BF8 { uint4 u; bf16x8 b; };
static __device__ __forceinline__ bf16x8 ldg_bf8(const u16* p) {
  BF8 t; t.u = *(const uint4*)p; return t.b;
}

// ---------------------------------------------------------------------------
// Transpose + fp32->bf16 convert: in (L,R,C) f32 -> out (L,C,R) bf16.
// grid = (C/32, R/32, L), block = 256
// ---------------------------------------------------------------------------
__global__ __launch_bounds__(256) void transpose_bf16(
    const float* __restrict__ in, u16* __restrict__ out, int R, int C)
{
  __shared__ float t[32][33];
  const size_t base = (size_t)blockIdx.z * R * C;
  const float* ip = in + base;
  u16* op = out + base;
  const int c0 = blockIdx.x * 32, r0 = blockIdx.y * 32;
  const int tx = threadIdx.x & 31, ty = threadIdx.x >> 5;  // 32 x 8
#pragma unroll
  for (int i = 0; i < 4; i++)
    t[ty + i * 8][tx] = ip[(size_t)(r0 + ty + i * 8) * C + (c0 + tx)];
  __syncthreads();
#pragma unroll
  for (int i = 0; i < 4; i++)
    op[(size_t)(c0 + ty + i * 8) * R + (r0 + tx)] = f2bf(t[tx][ty + i * 8]);
}

// ---------------------------------------------------------------------------
// Embedding gather: h[s][:] = tok_emb[tok[s]][:]. grid=2048, block=256
// ---------------------------------------------------------------------------
__global__ __launch_bounds__(256) void embed_k(
    const int* __restrict__ tok, const float* __restrict__ emb, float* __restrict__ h)
{
  const int s = blockIdx.x;
  const int t = tok[s];
  ((float4*)(h + (size_t)s * 1024))[threadIdx.x] =
      ((const float4*)(emb + (size_t)t * 1024))[threadIdx.x];
}

// ---------------------------------------------------------------------------
// RMSNorm row -> bf16. grid=2048 (one block/row), block=256 (4 elems/thread)
// ---------------------------------------------------------------------------
__global__ __launch_bounds__(256) void rmsnorm_bf16(
    const float* __restrict__ x, const float* __restrict__ w, u16* __restrict__ y)
{
  const int s = blockIdx.x, tid = threadIdx.x;
  const float4 v = ((const float4*)(x + (size_t)s * 1024))[tid];
  float ss = v.x * v.x + v.y * v.y + v.z * v.z + v.w * v.w;
#pragma unroll
  for (int off = 32; off; off >>= 1) ss += __shfl_xor(ss, off);
  __shared__ float red[4];
  if ((tid & 63) == 0) red[tid >> 6] = ss;
  __syncthreads();
  const float tot = red[0] + red[1] + red[2] + red[3];
  const float sc = rsqrtf(tot * (1.0f / 1024.0f) + 1e-6f);
  const float4 wv = ((const float4*)w)[tid];
  ushort4 o;
  o.x = f2bf(v.x * sc * wv.x);
  o.y = f2bf(v.y * sc * wv.y);
  o.z = f2bf(v.z * sc * wv.z);
  o.w = f2bf(v.w * sc * wv.w);
  ((ushort4*)(y + (size_t)s * 1024))[tid] = o;
}

// ---------------------------------------------------------------------------
// GEMM: C(MxN) [f32] = A(MxK)[bf16, lda=K] @ Bt(NxK)[bf16, ldb=K]^T  (+C if doAdd)
// m97 structure: 128x128 tile, BK=32, 4 waves (2x2), 4x4 16x16x32 frags/wave,
// global_load_lds width=16 staging. grid=(N/128, M/128, z); z picks B/C set.
// ---------------------------------------------------------------------------
__global__ __launch_bounds__(256) void gemm_bt(
    int M, int N, int K,
    const u16* __restrict__ A,
    const u16* __restrict__ Bz0, const u16* __restrict__ Bz1, const u16* __restrict__ Bz2,
    float* __restrict__ Cz0, float* __restrict__ Cz1, float* __restrict__ Cz2,
    int doAdd)
{
  const u16* B = (blockIdx.z == 0) ? Bz0 : (blockIdx.z == 1) ? Bz1 : Bz2;
  float*    C = (blockIdx.z == 0) ? Cz0 : (blockIdx.z == 1) ? Cz1 : Cz2;
  __shared__ u16 As[128 * 32];
  __shared__ u16 Bs[128 * 32];
  const int tid = threadIdx.x;
  const int wave = tid >> 6, lane = tid & 63;
  const int lm = lane & 15, quad = lane >> 4;
  const int wm = wave >> 1, wn = wave & 1;
  const int m0 = blockIdx.y * 128, n0 = blockIdx.x * 128;

  const int c0 = tid, c1 = tid + 256;
  const u16* ga0 = A + (size_t)(m0 + (c0 >> 2)) * K + (c0 & 3) * 8;
  const u16* ga1 = A + (size_t)(m0 + (c1 >> 2)) * K + (c1 & 3) * 8;
  const u16* gb0 = B + (size_t)(n0 + (c0 >> 2)) * K + (c0 & 3) * 8;
  const u16* gb1 = B + (size_t)(n0 + (c1 >> 2)) * K + (c1 & 3) * 8;
  u16* la0 = &As[c0 * 8];
  u16* la1 = &As[c1 * 8];
  u16* lb0 = &Bs[c0 * 8];
  u16* lb1 = &Bs[c1 * 8];

  f32x4 acc[4][4];
#pragma unroll
  for (int i = 0; i < 4; i++)
#pragma unroll
    for (int j = 0; j < 4; j++) acc[i][j] = (f32x4){0.f, 0.f, 0.f, 0.f};

  const u16* arp = &As[(wm * 64 + lm) * 32 + quad * 8];
  const u16* brp = &Bs[(wn * 64 + lm) * 32 + quad * 8];

  for (int k0 = 0; k0 < K; k0 += 32) {
    __syncthreads();
    gload16(ga0 + k0, la0);
    gload16(ga1 + k0, la1);
    gload16(gb0 + k0, lb0);
    gload16(gb1 + k0, lb1);
    __syncthreads();
    bf16x8 af[4], bfv[4];
#pragma unroll
    for (int mi = 0; mi < 4; mi++) af[mi] = *(const bf16x8*)(arp + mi * 16 * 32);
#pragma unroll
    for (int ni = 0; ni < 4; ni++) bfv[ni] = *(const bf16x8*)(brp + ni * 16 * 32);
#pragma unroll
    for (int mi = 0; mi < 4; mi++)
#pragma unroll
      for (int ni = 0; ni < 4; ni++)
        acc[mi][ni] = __builtin_amdgcn_mfma_f32_16x16x32_bf16(af[mi], bfv[ni], acc[mi][ni], 0, 0, 0);
  }

#pragma unroll
  for (int mi = 0; mi < 4; mi++) {
    const int row = m0 + wm * 64 + mi * 16 + quad * 4;
#pragma unroll
    for (int ni = 0; ni < 4; ni++) {
      const int col = n0 + wn * 64 + ni * 16 + lm;
      float* cp = C + (size_t)row * N + col;
      if (doAdd) {
#pragma unroll
        for (int r = 0; r < 4; r++) cp[(size_t)r * N] += acc[mi][ni][r];
      } else {
#pragma unroll
        for (int r = 0; r < 4; r++) cp[(size_t)r * N] = acc[mi][ni][r];
      }
    }
  }
}

// ---------------------------------------------------------------------------
// GEMM 128x64 tile variant, always C += A@B^T. grid=(N/64, M/128), block=256.
// ---------------------------------------------------------------------------
__global__ __launch_bounds__(256) void gemm_bt64(
    int M, int N, int K, const u16* __restrict__ A, const u16* __restrict__ B,
    float* __restrict__ C)
{
  __shared__ u16 As[128 * 32];
  __shared__ u16 Bs[64 * 32];
  const int tid = threadIdx.x;
  const int wave = tid >> 6, lane = tid & 63;
  const int lm = lane & 15, quad = lane >> 4;
  const int m0 = blockIdx.y * 128, n0 = blockIdx.x * 64;

  const int c0 = tid, c1 = tid + 256;
  const u16* ga0 = A + (size_t)(m0 + (c0 >> 2)) * K + (c0 & 3) * 8;
  const u16* ga1 = A + (size_t)(m0 + (c1 >> 2)) * K + (c1 & 3) * 8;
  const u16* gb0 = B + (size_t)(n0 + (c0 >> 2)) * K + (c0 & 3) * 8;
  u16* la0 = &As[c0 * 8];
  u16* la1 = &As[c1 * 8];
  u16* lb0 = &Bs[c0 * 8];

  f32x4 acc[2][4];
#pragma unroll
  for (int i = 0; i < 2; i++)
#pragma unroll
    for (int j = 0; j < 4; j++) acc[i][j] = (f32x4){0.f, 0.f, 0.f, 0.f};

  const u16* arp = &As[(wave * 32 + lm) * 32 + quad * 8];
  const u16* brp = &Bs[lm * 32 + quad * 8];

  for (int k0 = 0; k0 < K; k0 += 32) {
    __syncthreads();
    gload16(ga0 + k0, la0);
    gload16(ga1 + k0, la1);
    gload16(gb0 + k0, lb0);
    __syncthreads();
    bf16x8 af[2], bfv[4];
#pragma unroll
    for (int mi = 0; mi < 2; mi++) af[mi] = *(const bf16x8*)(arp + mi * 16 * 32);
#pragma unroll
    for (int ni = 0; ni < 4; ni++) bfv[ni] = *(const bf16x8*)(brp + ni * 16 * 32);
#pragma unroll
    for (int mi = 0; mi < 2; mi++)
#pragma unroll
      for (int ni = 0; ni < 4; ni++)
        acc[mi][ni] = __builtin_amdgcn_mfma_f32_16x16x32_bf16(af[mi], bfv[ni], acc[mi][ni], 0, 0, 0);
  }

#pragma unroll
  for (int mi = 0; mi < 2; mi++) {
    const int row = m0 + wave * 32 + mi * 16 + quad * 4;
#pragma unroll
    for (int ni = 0; ni < 4; ni++) {
      const int col = n0 + ni * 16 + lm;
      float* cp = C + (size_t)row * N + col;
#pragma unroll
      for (int r = 0; r < 4; r++) cp[(size_t)r * N] += acc[mi][ni][r];
    }
  }
}

// ---------------------------------------------------------------------------
// RoPE on q,k (fp32 in) -> bf16 out. grid = 4096, block = 256
// ---------------------------------------------------------------------------
__global__ __launch_bounds__(256) void rope_qk(
    const float* __restrict__ qf, const float* __restrict__ kf,
    u16* __restrict__ qb, u16* __restrict__ kb)
{
  const int idx = blockIdx.x * 256 + threadIdx.x;
  const int s = idx >> 9;          // 512 pairs per position
  const int p = idx & 511;
  const int h = p >> 5, i = p & 31;
  const size_t o = (size_t)s * 1024 + h * 64 + 2 * i;
  const float freq = __expf((float)i * (-9.210340371976184f / 32.0f)); // theta^{-2i/64}
  const float ang = (float)s * freq;
  float sn, cs;
  sincosf(ang, &sn, &cs);
  const float2 q = *(const float2*)(qf + o);
  const float2 k = *(const float2*)(kf + o);
  ushort2 qo, ko;
  qo.x = f2bf(q.x * cs - q.y * sn); qo.y = f2bf(q.x * sn + q.y * cs);
  ko.x = f2bf(k.x * cs - k.y * sn); ko.y = f2bf(k.x * sn + k.y * cs);
  *(ushort2*)(qb + o) = qo;
  *(ushort2*)(kb + o) = ko;
}

// ---------------------------------------------------------------------------
// Flash attention v2, causal, bf16 MFMA — swapped-QK^T + block-cooperative
// LDS staging of K/V tiles. grid=(32, 16 heads), block=256 (4 waves, 16 q ea).
//
// Round-3 diagnosis: per-wave scattered global K/V loads (16 cache lines per
// instr, x4 redundant across waves) saturate the vmem/L2 transaction path —
// waves sit in vmcnt waits (MfmaUtil & VALUBusy scaled down together). Fix:
// all 4 waves share one 64x64 K-tile + 64x64 V-tile per chunk, staged with
// 16 gload16/block (8 rows x 128B coalesced lines each), double-buffered,
// ONE __syncthreads per chunk (stage next issued before compute -> latency
// hidden; barrier drains vmcnt). XOR swizzle slot^=(row&7) applied on the
// GLOBAL source (gload_lds writes linearly) and on the ds_read side:
// K ds_read_b128 conflict-free, V ds_read_b64 <=4-way.
//
// Compute structure (verified round 3): S=mfma(A=K,B=Q) -> lane holds 16
// scores for one query (keys 16j+4q+r); in-lane softmax (2 shfl_xor per
// reduce); P packed in-lane; PV uses bijection (quad,jj)->key =
// 32h+16*(jj>=4)+4quad+(jj&3) on both P(A) and V(B).
// ---------------------------------------------------------------------------
__global__ __launch_bounds__(256) void attn_fa(
    const u16* __restrict__ Q, const u16* __restrict__ Kb,
    const u16* __restrict__ Vt, u16* __restrict__ O)
{
  const int head = blockIdx.y;
  const int tid = threadIdx.x;
  const int wave = tid >> 6, lane = tid & 63;
  const int lm = lane & 15, quad = lane >> 4;
  const int qblk = 31 - blockIdx.x;          // longest first
  const int q0 = qblk * 64 + wave * 16;
  const int nc = qblk + 1;                   // 64-key chunks (uniform per block)
  const float sc_l2 = 0.125f * 1.4426950408889634f;  // 1/sqrt(64) * log2(e)
  const int qrow = q0 + lm;                  // this lane's query (softmax layout)

  // K tile: [64 keys][64 d] bf16, 128B rows; V tile: [64 d][64 keys] bf16.
  // Physical 16B-slot s_phys of row holds logical slot s_phys ^ (row&7).
  __shared__ __align__(16) u16 Kt[2][64 * 64];
  __shared__ __align__(16) u16 Vl[2][64 * 64];

  const u16* qp = Q + (size_t)(q0 + lm) * 1024 + head * 64 + quad * 8;
  const bf16x8 aq0 = ldg_bf8(qp);        // Q[q=lm][d=quad*8+j], d 0..31 (B-frag)
  const bf16x8 aq1 = ldg_bf8(qp + 32);   // d 32..63

  f32x4 o[4];
#pragma unroll
  for (int i = 0; i < 4; i++) o[i] = (f32x4){0.f, 0.f, 0.f, 0.f};
  float mrun = -1e30f;   // per-lane running max (log2 domain), query qrow
  float lrun = 0.f;      // per-lane running denom, query qrow

  // stage K+V tiles for chunk at kc into buffer buf. 256 threads, 4 gload16
  // each; per instr: 8 rows x 128B fully-coalesced. Source pre-swizzled.
  auto stage = [&](int kc, int buf) {
#pragma unroll
    for (int p = 0; p < 2; p++) {
      const int row = p * 32 + (tid >> 3);
      const int sg = (tid & 7) ^ (row & 7);
      gload16(Kb + (size_t)(kc + row) * 1024 + head * 64 + sg * 8,
              &Kt[buf][(p * 256 + tid) * 8]);
    }
#pragma unroll
    for (int p = 0; p < 2; p++) {
      const int row = p * 32 + (tid >> 3);
      const int sg = (tid & 7) ^ (row & 7);
      gload16(Vt + (size_t)(head * 64 + row) * 2048 + kc + sg * 8,
              &Vl[buf][(p * 256 + tid) * 8]);
    }
  };

  auto compute = [&](int kc, int buf) {
    const u16* Kl = &Kt[buf][0];
    const u16* Vb = &Vl[buf][0];
    // V frags from LDS; bijection (quad,jj)->key = 32h+16*(jj>=4)+4q+(jj&3).
    BF8 vv[2][4];
#pragma unroll
    for (int h = 0; h < 2; h++)
#pragma unroll
      for (int nd = 0; nd < 4; nd++) {
        const int row = nd * 16 + lm;
        const int sl = (4 * h + (quad >> 1)) ^ (lm & 7);       // keys 32h+4q+0..3
        const int sh = (4 * h + 2 + (quad >> 1)) ^ (lm & 7);   // keys +16
        const uint2 lo = *(const uint2*)&Vb[row * 64 + sl * 8 + (quad & 1) * 4];
        const uint2 hi = *(const uint2*)&Vb[row * 64 + sh * 8 + (quad & 1) * 4];
        vv[h][nd].u = (uint4){lo.x, lo.y, hi.x, hi.y};
      }
    // K frags: kr[j*2+e] = K[key=16j+lm][d = e*32 + quad*8 .. +8]
    bf16x8 kr[8];
#pragma unroll
    for (int j = 0; j < 4; j++)
#pragma unroll
      for (int e = 0; e < 2; e++)
        kr[j * 2 + e] = *(const bf16x8*)
            &Kl[(16 * j + lm) * 64 + (((4 * e + quad) ^ (lm & 7)) * 8)];

    const f32x4 z = (f32x4){0.f, 0.f, 0.f, 0.f};
    f32x4 S[4];
#pragma unroll
    for (int j = 0; j < 4; j++) {
      S[j] = __builtin_amdgcn_mfma_f32_16x16x32_bf16(kr[j * 2 + 0], aq0, z, 0, 0, 0);
      S[j] = __builtin_amdgcn_mfma_f32_16x16x32_bf16(kr[j * 2 + 1], aq1, S[j], 0, 0, 0);
    }
    // per-lane: 16 scores for query qrow, key(j,r) = kc + 16j + 4*quad + r
    float p[4][4];
#pragma unroll
    for (int j = 0; j < 4; j++)
#pragma unroll
      for (int r = 0; r < 4; r++) p[j][r] = S[j][r] * sc_l2;
    if (kc + 63 > q0) {                       // wave-uniform: chunk hits diagonal
#pragma unroll
      for (int j = 0; j < 4; j++)
#pragma unroll
        for (int r = 0; r < 4; r++)
          if (kc + 16 * j + 4 * quad + r > qrow) p[j][r] = -1e30f;
    }
    float mx = -1e30f;
#pragma unroll
    for (int j = 0; j < 4; j++)
#pragma unroll
      for (int r = 0; r < 4; r++) mx = fmaxf(mx, p[j][r]);
    mx = fmaxf(mx, __shfl_xor(mx, 16));
    mx = fmaxf(mx, __shfl_xor(mx, 32));       // now quad-uniform per query lm
    const float mnew = fmaxf(mrun, mx);
    const float alpha = exp2f(mrun - mnew);
    mrun = mnew;
    float rs = 0.f;
#pragma unroll
    for (int j = 0; j < 4; j++)
#pragma unroll
      for (int r = 0; r < 4; r++) {
        p[j][r] = exp2f(p[j][r] - mnew);
        rs += p[j][r];
      }
    rs += __shfl_xor(rs, 16);
    rs += __shfl_xor(rs, 32);
    lrun = lrun * alpha + rs;
    // alpha lives at query=lm; o rows are query=4*quad+r -> broadcast
    float alr[4];
#pragma unroll
    for (int r = 0; r < 4; r++) alr[r] = __shfl(alpha, quad * 4 + r);
#pragma unroll
    for (int nd = 0; nd < 4; nd++)
#pragma unroll
      for (int r = 0; r < 4; r++) o[nd][r] *= alr[r];
    // pack P A-frags fully in-lane: fa[h] jj<4 = p[2h][jj], jj>=4 = p[2h+1][jj-4]
    BF8 fa[2];
#pragma unroll
    for (int h = 0; h < 2; h++) {
      u16* s = (u16*)&fa[h];
#pragma unroll
      for (int r = 0; r < 4; r++) {
        s[r]     = f2bf(p[2 * h][r]);
        s[4 + r] = f2bf(p[2 * h + 1][r]);
      }
    }
#pragma unroll
    for (int h = 0; h < 2; h++)
#pragma unroll
      for (int nd = 0; nd < 4; nd++)
        o[nd] = __builtin_amdgcn_mfma_f32_16x16x32_bf16(fa[h].b, vv[h][nd].b, o[nd], 0, 0, 0);
  };

  stage(0, 0);
  __syncthreads();                 // drains stage vmcnt, syncs all waves
  for (int c = 0; c < nc; c++) {
    if (c + 1 < nc) stage((c + 1) * 64, (c + 1) & 1);
    compute(c * 64, c & 1);
    if (c + 1 < nc) __syncthreads();   // wave-uniform; drains next-stage DMA
  }

  // lrun lives at query=lm; o rows are query=4*quad+r -> broadcast
#pragma unroll
  for (int r = 0; r < 4; r++) {
    const float linv = 1.0f / __shfl(lrun, quad * 4 + r);
    const int row = q0 + quad * 4 + r;
    u16* op = O + (size_t)row * 1024 + head * 64 + lm;
#pragma unroll
    for (int nd = 0; nd < 4; nd++) op[nd * 16] = f2bf(o[nd][r] * linv);
  }
}

// ---------------------------------------------------------------------------
// u = bf16( silu(g1) * g3 ). grid=5632, block=256, float4 per thread.
// ---------------------------------------------------------------------------
__global__ __launch_bounds__(256) void silu_mul(
    const float* __restrict__ g1, const float* __restrict__ g3, u16* __restrict__ u)
{
  const int idx = blockIdx.x * 256 + threadIdx.x;
  const float4 a = ((const float4*)g1)[idx];
  const float4 b = ((const float4*)g3)[idx];
  ushort4 o;
  o.x = f2bf(a.x / (1.f + __expf(-a.x)) * b.x);
  o.y = f2bf(a.y / (1.f + __expf(-a.y)) * b.y);
  o.z = f2bf(a.z / (1.f + __expf(-a.z)) * b.z);
  o.w = f2bf(a.w / (1.f + __expf(-a.w)) * b.w);
  ((ushort4*)u)[idx] = o;
}

// ---------------------------------------------------------------------------
// Final RMSNorm of last row (fp32 out). 1 block, 256 threads.
// ---------------------------------------------------------------------------
__global__ __launch_bounds__(256) void final_norm(
    const float* __restrict__ h, const float* __restrict__ w, float* __restrict__ xn)
{
  const int tid = threadIdx.x;
  const float4 v = ((const float4*)(h + (size_t)2047 * 1024))[tid];
  float ss = v.x * v.x + v.y * v.y + v.z * v.z + v.w * v.w;
#pragma unroll
  for (int off = 32; off; off >>= 1) ss += __shfl_xor(ss, off);
  __shared__ float red[4];
  if ((tid & 63) == 0) red[tid >> 6] = ss;
  __syncthreads();
  const float tot = red[0] + red[1] + red[2] + red[3];
  const float sc = rsqrtf(tot * (1.0f / 1024.0f) + 1e-6f);
  const float4 wv = ((const float4*)w)[tid];
  float4 o;
  o.x = v.x * sc * wv.x; o.y = v.y * sc * wv.y;
  o.z = v.z * sc * wv.z; o.w = v.w * sc * wv.w;
  ((float4*)xn)[tid] = o;
}

// ---------------------------------------------------------------------------
// logits[v] += sum over 256-d slice of xn[d]*Wout[d][v]. grid=(125,4), fp32.
// ---------------------------------------------------------------------------
__global__ __launch_bounds__(256) void logits_k(
    const float* __restrict__ xn, const float* __restrict__ Wout, float* __restrict__ out)
{
  const int v = blockIdx.x * 256 + threadIdx.x;
  const int dp = blockIdx.y;
  const float* xp = xn + dp * 256;
  const float* wp = Wout + (size_t)dp * 256 * 32000 + v;
  float acc = 0.f;
#pragma unroll 8
  for (int d = 0; d < 256; d++) acc = fmaf(xp[d], wp[(size_t)d * 32000], acc);
  atomicAdd(out + v, acc);
}

// ---------------------------------------------------------------------------
extern "C" void kernel_launch(void* const* d_in, const int* in_sizes, int n_in,
                              void* d_out, int out_size, void* d_ws, size_t ws_size,
                              hipStream_t stream) {
  const int S = 2048, D = 1024, HFF = 2816, L = 4;
  const int* tokens = (const int*)d_in[0];
  const float* tok_emb = (const float*)d_in[2];
  const float* Wq = (const float*)d_in[3];
  const float* Wk = (const float*)d_in[4];
  const float* Wv = (const float*)d_in[5];
  const float* Wo = (const float*)d_in[6];
  const float* W1 = (const float*)d_in[7];
  const float* W2 = (const float*)d_in[8];   // dict order: W2 before W3
  const float* W3 = (const float*)d_in[9];
  const float* anw  = (const float*)d_in[10];
  const float* fnw  = (const float*)d_in[11];
  const float* finw = (const float*)d_in[12];
  const float* Wout = (const float*)d_in[13];

  char* w = (char*)d_ws;
  size_t off = 0;
  auto take = [&](size_t b) { size_t o = off; off += (b + 255) & ~(size_t)255; return o; };
  const size_t szDD = (size_t)L * D * D * 2;       // 8 MB bf16
  const size_t szDH = (size_t)L * D * HFF * 2;     // 23 MB bf16
  u16* WqT = (u16*)(w + take(szDD));
  u16* WkT = (u16*)(w + take(szDD));
  u16* WvT = (u16*)(w + take(szDD));
  u16* WoT = (u16*)(w + take(szDD));
  u16* W1T = (u16*)(w + take(szDH));
  u16* W3T = (u16*)(w + take(szDH));
  u16* W2T = (u16*)(w + take(szDH));
  float* h  = (float*)(w + take((size_t)S * D * 4));
  u16*   xb = (u16*)(w + take((size_t)S * D * 2));
  const size_t region = take((size_t)2 * S * HFF * 4 + (size_t)S * HFF * 2);
  float* qf = (float*)(w + region);
  float* kf = qf + (size_t)S * D;
  float* vf = kf + (size_t)S * D;
  u16* qbb = (u16*)(vf + (size_t)S * D);
  u16* kbb = qbb + (size_t)S * D;
  u16* vTb = kbb + (size_t)S * D;
  u16* ob  = vTb + (size_t)S * D;
  float* g1 = (float*)(w + region);
  float* g3 = g1 + (size_t)S * HFF;
  u16*  ub  = (u16*)(g3 + (size_t)S * HFF);
  float* xn = (float*)(w + take(4096));
  (void)ws_size; (void)in_sizes; (void)n_in; (void)out_size;

  const dim3 blk(256);
  transpose_bf16<<<dim3(32, 32, 4), blk, 0, stream>>>(Wq, WqT, D, D);
  transpose_bf16<<<dim3(32, 32, 4), blk, 0, stream>>>(Wk, WkT, D, D);
  transpose_bf16<<<dim3(32, 32, 4), blk, 0, stream>>>(Wv, WvT, D, D);
  transpose_bf16<<<dim3(32, 32, 4), blk, 0, stream>>>(Wo, WoT, D, D);
  transpose_bf16<<<dim3(88, 32, 4), blk, 0, stream>>>(W1, W1T, D, HFF);
  transpose_bf16<<<dim3(88, 32, 4), blk, 0, stream>>>(W3, W3T, D, HFF);
  transpose_bf16<<<dim3(32, 88, 4), blk, 0, stream>>>(W2, W2T, HFF, D);
  embed_k<<<2048, blk, 0, stream>>>(tokens, tok_emb, h);

  for (int l = 0; l < L; l++) {
    const size_t oDD = (size_t)l * D * D;
    const size_t oDH = (size_t)l * D * HFF;
    rmsnorm_bf16<<<2048, blk, 0, stream>>>(h, anw + l * D, xb);
    gemm_bt<<<dim3(8, 16, 3), blk, 0, stream>>>(S, D, D, xb,
        WqT + oDD, WkT + oDD, WvT + oDD, qf, kf, vf, 0);
    rope_qk<<<4096, blk, 0, stream>>>(qf, kf, qbb, kbb);
    transpose_bf16<<<dim3(32, 64, 1), blk, 0, stream>>>(vf, vTb, S, D);
    attn_fa<<<dim3(32, 16), blk, 0, stream>>>(qbb, kbb, vTb, ob);
    gemm_bt64<<<dim3(16, 16), blk, 0, stream>>>(S, D, D, ob, WoT + oDD, h);
    rmsnorm_bf16<<<2048, blk, 0, stream>>>(h, fnw + l * D, xb);
    gemm_bt<<<dim3(22, 16, 2), blk, 0, stream>>>(S, HFF, D, xb,
        W1T + oDH, W3T + oDH, W3T + oDH, g1, g3, g3, 0);
    silu_mul<<<5632, blk, 0, stream>>>(g1, g3, ub);
    gemm_bt64<<<dim3(16, 16), blk, 0, stream>>>(S, D, HFF, ub, W2T + oDH, h);
  }
  final_norm<<<1, blk, 0, stream>>>(h, finw, xn);
  hipMemsetAsync(d_out, 0, 32000 * sizeof(float), stream);
  logits_k<<<dim3(125, 4), blk, 0, stream>>>(xn, Wout, (float*)d_out);
}